// Round 14
// baseline (350.930 us; speedup 1.0000x reference)
//
#include <hip/hip_runtime.h>
#include <cstdint>
#include <cstddef>

#define Tt 2048
#define Hh 1024
#define Ff 3584
#define Ee 8
#define NP 7168
#define MAXT 40
#define MAXT2 24

#define OFF_CTRL   0u
#define OFF_TOKE   4096u
#define OFF_TOKW   (4096u + 16384u)
#define OFF_ROWMAP 65536u
#define OFF_ROWW   98304u
#define OFF_XG     262144ull
#define OFF_G      11272192ull            // Xg spacing 5376 rows (tile over-read safe)
#define OFF_W13T   47972352ull            // 8*7168*1024*2 = 117,440,512
#define OFF_W2T    165412864ull           // ends 224,133,120 (~213.8 MiB < 216 proven)

typedef __attribute__((ext_vector_type(8))) short bf16x8;
typedef __attribute__((ext_vector_type(4))) float f32x4;

__device__ __forceinline__ unsigned short f2bf(float f) {
  unsigned int u = __float_as_uint(f);
  u += 0x7fffu + ((u >> 16) & 1u);
  return (unsigned short)(u >> 16);
}

__device__ __forceinline__ unsigned pkbf(float a, float b) {
  unsigned r;
  asm("v_cvt_pk_bf16_f32 %0, %1, %2" : "=v"(r) : "v"(a), "v"(b));
  return r;
}

__device__ __forceinline__ void gload_lds16(const void* g, void* l) {
  auto gp = (const __attribute__((address_space(1))) char*)(uintptr_t)g;
  auto lp = (__attribute__((address_space(3))) char*)(uintptr_t)l;
  __builtin_amdgcn_global_load_lds(gp, lp, 16, 0, 0);
}

// GEMM LDS tile: rows x 32k bf16 (64 B/row); chunk gc at pos = gc ^ ((row>>1)&3).
__device__ __forceinline__ bf16x8 frg(const char* lds, int row, int gc) {
  return *(const bf16x8*)(lds + row * 64 + ((gc ^ ((row >> 1) & 3)) * 16));
}

// ---- tc tile (256-thr unit): fp32 [.][C] rows r0g..+127 x cols c0..+63 -> bf16 [col][row].
// mode 0: out row = c (plain transpose).  mode 1/2: W13T interleave
//   out row = ((c>>4)<<5) + (c&15) + (mode==2 ? 16 : 0)   (w1 even 16-block, w3 odd)
__device__ __forceinline__ void tc_tile(const float* __restrict__ src,
                                        unsigned short* __restrict__ dst,
                                        int R, int C, int r0g, int c0,
                                        char* sT, int t, int mode) {
  const int col4 = (t & 15) * 4, rb = (t >> 4) * 8;
  float4 v[8];
#pragma unroll
  for (int i = 0; i < 8; ++i)
    v[i] = *(const float4*)(src + (size_t)(r0g + rb + i) * C + c0 + col4);
#pragma unroll
  for (int j = 0; j < 4; ++j) {
    int c = col4 + j;
    int M = (((c & 7) ^ ((c >> 3) & 7)) << 4);
    uint4 q;
    q.x = pkbf(((const float*)&v[0])[j], ((const float*)&v[1])[j]);
    q.y = pkbf(((const float*)&v[2])[j], ((const float*)&v[3])[j]);
    q.z = pkbf(((const float*)&v[4])[j], ((const float*)&v[5])[j]);
    q.w = pkbf(((const float*)&v[6])[j], ((const float*)&v[7])[j]);
    *(uint4*)(sT + c * 256 + ((rb * 2) ^ M)) = q;
  }
  __syncthreads();
  const int oc = t >> 2, part = t & 3;
  const int M = (((oc & 7) ^ ((oc >> 3) & 7)) << 4);
  int cg = c0 + oc;
  int orow = (mode == 0) ? cg : (((cg >> 4) << 5) + (cg & 15) + (mode == 2 ? 16 : 0));
#pragma unroll
  for (int i = 0; i < 4; ++i) {
    uint4 q = *(const uint4*)(sT + oc * 256 + ((i * 64 + part * 16) ^ M));
    *(uint4*)(dst + (size_t)orow * R + r0g + i * 32 + part * 8) = q;
  }
}

// ---------------- K1: router (0..511) || tc(w1->W13T even) (512..4095) ----------------
__global__ __launch_bounds__(256) void router_tc1(
    const float* __restrict__ x, const float* __restrict__ gw,
    float* __restrict__ logits_out, int* __restrict__ tok_e,
    float* __restrict__ tok_w, int* __restrict__ ctrl,
    const float* __restrict__ w1, unsigned short* __restrict__ w13T) {
  __shared__ alignas(16) char sT[16384];
  if (blockIdx.x >= 512) {
    int b = blockIdx.x - 512;                 // 448 tiles/expert: 8 r x 56 c
    int e = b / 448, rem = b % 448;
    int tr = rem / 56, tcc = rem % 56;
    tc_tile(w1 + (size_t)e * Hh * Ff, w13T + (size_t)e * NP * Hh,
            Hh, Ff, tr * 128, tcc * 64, sT, threadIdx.x, 1);
    return;
  }
  const int lane = threadIdx.x & 63;
  const int t = blockIdx.x * 4 + (threadIdx.x >> 6);
  const float4* xp = (const float4*)(x + (size_t)t * Hh + lane * 16);
  float4 x0 = xp[0], x1 = xp[1], x2 = xp[2], x3 = xp[3];
  float lg[Ee];
#pragma unroll
  for (int e = 0; e < Ee; ++e) {
    const float4* gp = (const float4*)(gw + e * Hh + lane * 16);
    float4 g0 = gp[0], g1 = gp[1], g2 = gp[2], g3 = gp[3];
    float s = x0.x*g0.x + x0.y*g0.y + x0.z*g0.z + x0.w*g0.w
            + x1.x*g1.x + x1.y*g1.y + x1.z*g1.z + x1.w*g1.w
            + x2.x*g2.x + x2.y*g2.y + x2.z*g2.z + x2.w*g2.w
            + x3.x*g3.x + x3.y*g3.y + x3.z*g3.z + x3.w*g3.w;
#pragma unroll
    for (int o = 32; o; o >>= 1) s += __shfl_xor(s, o);
    lg[e] = s;
  }
  if (lane == 0) {
    float m = lg[0];
#pragma unroll
    for (int e = 1; e < Ee; ++e) m = fmaxf(m, lg[e]);
    float p[Ee];
#pragma unroll
    for (int e = 0; e < Ee; ++e) p[e] = expf(lg[e] - m);
    int a0 = 0;
#pragma unroll
    for (int e = 1; e < Ee; ++e) if (p[e] > p[a0]) a0 = e;
    int a1 = (a0 == 0) ? 1 : 0;
#pragma unroll
    for (int e = 0; e < Ee; ++e) if (e != a0 && p[e] > p[a1]) a1 = e;
    float rs = p[a0] + p[a1];
    float w0 = p[a0] / rs, w1v = p[a1] / rs;
#pragma unroll
    for (int e = 0; e < Ee; ++e) logits_out[(size_t)t * Ee + e] = lg[e];
    tok_e[t * 2] = a0; tok_e[t * 2 + 1] = a1;
    tok_w[t * 2] = w0; tok_w[t * 2 + 1] = w1v;
    atomicAdd(&ctrl[a0], 1); atomicAdd(&ctrl[a1], 1);
  }
}

// offsets + 128-table (ctrl[32..]) + 256-table (ctrl[128..]: e,row0,off1 triples)
__global__ void offsets_kernel(int* ctrl) {
  if (threadIdx.x == 0) {
    int acc = 0;
    for (int e = 0; e < Ee; ++e) {
      ctrl[16 + e] = acc;
      acc += ((ctrl[e] + 127) >> 7) << 7;
    }
    ctrl[16 + Ee] = acc;
    int idx = 0;
    for (int e = 0; e < Ee; ++e) {
      int nt = (ctrl[e] + 127) >> 7;
      for (int m = 0; m < nt && idx < MAXT; ++m) {
        ctrl[32 + 2 * idx] = e;
        ctrl[33 + 2 * idx] = ctrl[16 + e] + m * 128;
        ++idx;
      }
    }
    for (; idx < MAXT; ++idx) { ctrl[32 + 2 * idx] = 0; ctrl[33 + 2 * idx] = -1; }
    int idx2 = 0;
    for (int e = 0; e < Ee; ++e) {
      int sz = ((ctrl[e] + 127) >> 7) << 7;
      int nt = (sz + 255) >> 8;
      for (int m = 0; m < nt && idx2 < MAXT2; ++m) {
        ctrl[128 + 3 * idx2] = e;
        ctrl[129 + 3 * idx2] = ctrl[16 + e] + m * 256;
        ctrl[130 + 3 * idx2] = ctrl[16 + e] + sz;
        ++idx2;
      }
    }
    for (; idx2 < MAXT2; ++idx2) { ctrl[128 + 3 * idx2] = 0; ctrl[129 + 3 * idx2] = -1; ctrl[130 + 3 * idx2] = 0; }
  }
}

__global__ __launch_bounds__(512) void assign_kernel(
    int* ctrl, const int* __restrict__ tok_e, const float* __restrict__ tok_w,
    int* __restrict__ rowmap, float* __restrict__ roww) {
  int i = blockIdx.x * 512 + threadIdx.x;
  if (i < 2 * Tt) {
    int e = tok_e[i];
    int pos = atomicAdd(&ctrl[8 + e], 1);
    int r = ctrl[16 + e] + pos;
    rowmap[r] = i >> 1;
    roww[r] = tok_w[i];
  }
  if (i < Ee * 128) {
    int e = i >> 7, pd = i & 127;
    int o = ctrl[16 + e], o1 = ctrl[16 + e + 1], c = ctrl[e];
    int r = o + c + pd;
    if (r < o1) { rowmap[r] = -1; roww[r] = 0.f; }
  }
}

// ---------------- K4: gather (0..2559) || tc(w3->W13T odd) (2560..6143) ----------------
__global__ __launch_bounds__(256) void gather_tc3(
    const float* __restrict__ x, const int* __restrict__ ctrl,
    const int* __restrict__ rowmap, unsigned short* __restrict__ Xg,
    const float* __restrict__ w3, unsigned short* __restrict__ w13T) {
  __shared__ alignas(16) char sT[16384];
  if (blockIdx.x >= 2560) {
    int b = blockIdx.x - 2560;
    int e = b / 448, rem = b % 448;
    int tr = rem / 56, tcc = rem % 56;
    tc_tile(w3 + (size_t)e * Hh * Ff, w13T + (size_t)e * NP * Hh,
            Hh, Ff, tr * 128, tcc * 64, sT, threadIdx.x, 2);
    return;
  }
  int r = blockIdx.x * 2 + (threadIdx.x >> 7);
  int j = threadIdx.x & 127;
  if (r >= ctrl[16 + Ee]) return;
  int t = rowmap[r];
  uint4 v = make_uint4(0u, 0u, 0u, 0u);
  if (t >= 0) {
    const float4* xp = (const float4*)(x + (size_t)t * Hh + j * 8);
    float4 a = xp[0], b = xp[1];
    v.x = (unsigned)f2bf(a.x) | ((unsigned)f2bf(a.y) << 16);
    v.y = (unsigned)f2bf(a.z) | ((unsigned)f2bf(a.w) << 16);
    v.z = (unsigned)f2bf(b.x) | ((unsigned)f2bf(b.y) << 16);
    v.w = (unsigned)f2bf(b.z) | ((unsigned)f2bf(b.w) << 16);
  }
  *(uint4*)(Xg + (size_t)r * Hh + j * 8) = v;
}

// ---- K5: h13 256x256 (lin 0..671) || tc(w2) (672..1567, 4 tiles/block) ----
// h13: G[row][f] = silu(h1)*h3 from one GEMM vs interleaved W13T.
// d=3 pure-glds, uniform 2 glds/wave/iter. Ledger at loop wait:
//   in-flight = [stage(it+1)x2 (issued LAST iter), stage(it+2)x2 (this iter)] = 4
//   -> vmcnt(2) drains stage(it+1) (aged one full iter). it==30 -> vmcnt(0). it==31 none.
__global__ __launch_bounds__(1024, 4) void h13_tc2(
    const unsigned short* __restrict__ Xg, const unsigned short* __restrict__ w13T,
    const int* __restrict__ ctrl, unsigned short* __restrict__ G,
    const float* __restrict__ w2, unsigned short* __restrict__ w2T) {
  __shared__ alignas(16) char sLDS[98304];   // A: 3x16K @0 ; B: 3x16K @49152
  int lin = blockIdx.y * 28 + blockIdx.x;    // 0..1567
  if (lin >= 672) {
    int idx = lin - 672;                     // 0..895
    int s = threadIdx.x >> 8;                // 4 tc tiles per 1024-thr block
    int tile = idx * 4 + s;                  // 0..3583 ; w2: 28 r-tiles x 16 c-tiles
    int e = tile / 448, rem = tile % 448;
    int tr = rem / 16, tcc = rem % 16;
    tc_tile(w2 + (size_t)e * Ff * Hh, w2T + (size_t)e * Ff * Hh,
            Ff, Hh, tr * 128, tcc * 64, sLDS + s * 16384, threadIdx.x & 255, 0);
    return;
  }
  int wg = (lin & 7) * 84 + (lin >> 3);      // 672 = 8*84, XCD chunk
  int ft = wg % 24, bx = wg / 24;            // ft fast -> B-panel L2 reuse
  const int e = ctrl[128 + 3 * ft];
  const int row0 = ctrl[129 + 3 * ft];
  const int off1 = ctrl[130 + 3 * ft];
  if (row0 < 0) return;
  const int n0 = bx * 256;
  const int tid = threadIdx.x, lane = tid & 63, wv = tid >> 6;  // 16 waves 4x4
  const int wr = wv >> 2, wc = wv & 3;       // wave tile 64x64
  const unsigned short* wB = w13T + (size_t)e * NP * Hh;
  f32x4 acc[4][4] = {};
  const int srow = wv * 16 + (lane >> 2);
  const int sgc = (lane & 3) ^ ((lane >> 3) & 3);
  const unsigned short* gA = Xg + (size_t)(row0 + srow) * Hh + sgc * 8;
  const unsigned short* gB = wB + (size_t)(n0 + srow) * Hh + sgc * 8;
  char *cA = sLDS,          *nA = sLDS + 16384, *xA = sLDS + 32768;
  char *cB = sLDS + 49152,  *nB = sLDS + 65536, *xB = sLDS + 81920;

  // prologue: stage(0)->c, stage(1)->n, hard order-independent drain
  gload_lds16(gA, cA + wv * 1024);
  gload_lds16(gB, cB + wv * 1024);
  __builtin_amdgcn_sched_barrier(0);
  gload_lds16(gA + 32, nA + wv * 1024);
  gload_lds16(gB + 32, nB + wv * 1024);
  asm volatile("s_waitcnt vmcnt(0) lgkmcnt(0)" ::: "memory");
  __builtin_amdgcn_s_barrier();
  __builtin_amdgcn_sched_barrier(0);

  for (int it = 0; it < 32; ++it) {
    if (it < 30) {
      gload_lds16(gA + (size_t)(it + 2) * 32, xA + wv * 1024);
      gload_lds16(gB + (size_t)(it + 2) * 32, xB + wv * 1024);
    }
    __builtin_amdgcn_sched_barrier(0);
    {
      const int gc = lane >> 4;
      bf16x8 af[4];
#pragma unroll
      for (int mi = 0; mi < 4; ++mi)
        af[mi] = frg(cA, wr * 64 + mi * 16 + (lane & 15), gc);
      __builtin_amdgcn_s_setprio(1);
#pragma unroll
      for (int ni = 0; ni < 4; ++ni) {
        bf16x8 b = frg(cB, wc * 64 + ni * 16 + (lane & 15), gc);
#pragma unroll
        for (int mi = 0; mi < 4; ++mi)
          acc[mi][ni] = __builtin_amdgcn_mfma_f32_16x16x32_bf16(af[mi], b, acc[mi][ni], 0, 0, 0);
      }
      __builtin_amdgcn_s_setprio(0);
    }
    if (it < 31) {
      if (it < 30) asm volatile("s_waitcnt vmcnt(2) lgkmcnt(0)" ::: "memory");
      else         asm volatile("s_waitcnt vmcnt(0) lgkmcnt(0)" ::: "memory");
      __builtin_amdgcn_s_barrier();
      __builtin_amdgcn_sched_barrier(0);
    }
    { char* t_ = cA; cA = nA; nA = xA; xA = t_;
      t_ = cB; cB = nB; nB = xB; xB = t_; }
  }
  // epilogue: pair (ni even = w1-block, ni odd = w3-block of same f range)
  const int rb = wr * 64 + 4 * (lane >> 4);
  const int f0 = (n0 >> 1) + wc * 32 + (lane & 15);
#pragma unroll
  for (int mi = 0; mi < 4; ++mi)
#pragma unroll
    for (int r = 0; r < 4; ++r) {
      int grow = row0 + rb + mi * 16 + r;
      if (grow >= off1) continue;
#pragma unroll
      for (int nq = 0; nq < 2; ++nq) {
        float h1 = acc[mi][2 * nq][r], h3 = acc[mi][2 * nq + 1][r];
        float gv = h1 / (1.f + __expf(-h1)) * h3;
        G[(size_t)grow * Ff + f0 + nq * 16] = f2bf(gv);
      }
    }
}

// ---------------- K6: ffn2 128x128 d=3 aged (uniform 2 glds/wave/iter) ----------------
// Ledger: steady vmcnt(2); it==NT-2 -> vmcnt(0); it==NT-1 none. NT=28, ksplit x4.
__global__ __launch_bounds__(512, 4) void ffn2_gemm(
    const unsigned short* __restrict__ G, const unsigned short* __restrict__ w2T,
    const int* __restrict__ ctrl, const int* __restrict__ rowmap,
    const float* __restrict__ roww, float* __restrict__ out) {
  __shared__ alignas(16) char sLDS[49152];   // A: 3x8K @0 ; B: 3x8K @24576
  int lin = (blockIdx.z * MAXT + blockIdx.y) * 8 + blockIdx.x;  // 0..1279
  int wg = (lin & 7) * 160 + (lin >> 3);
  int ft = wg % 40, q = wg / 40;
  int bx = q & 7, ks = q >> 3;
  const int e = ctrl[32 + 2 * ft];
  const int row0 = ctrl[33 + 2 * ft];
  if (row0 < 0) return;
  const int n0 = bx * 128;
  const int kb = ks * (Ff / 4);
  const int tid = threadIdx.x, lane = tid & 63, wv = tid >> 6;
  const int wr = wv >> 2, wc = wv & 3;       // wave tile 64x32
  const unsigned short* w2e = w2T + (size_t)e * Ff * Hh;
  f32x4 acc[4][2] = {};
  const int srow = wv * 16 + (lane >> 2);
  const int sgc = (lane & 3) ^ ((lane >> 3) & 3);
  const unsigned short* gA = G   + (size_t)(row0 + srow) * Ff + kb + sgc * 8;
  const unsigned short* gB = w2e + (size_t)(n0 + srow) * Ff + kb + sgc * 8;
  char *cA = sLDS,         *nA = sLDS + 8192,  *xA = sLDS + 16384;
  char *cB = sLDS + 24576, *nB = sLDS + 32768, *xB = sLDS + 40960;

  gload_lds16(gA, cA + wv * 1024);
  gload_lds16(gB, cB + wv * 1024);
  __builtin_amdgcn_sched_barrier(0);
  gload_lds16(gA + 32, nA + wv * 1024);
  gload_lds16(gB + 32, nB + wv * 1024);
  asm volatile("s_waitcnt vmcnt(0) lgkmcnt(0)" ::: "memory");
  __builtin_amdgcn_s_barrier();
  __builtin_amdgcn_sched_barrier(0);

  const int NT = 28;
  for (int it = 0; it < NT; ++it) {
    if (it < NT - 2) {
      gload_lds16(gA + (size_t)(it + 2) * 32, xA + wv * 1024);
      gload_lds16(gB + (size_t)(it + 2) * 32, xB + wv * 1024);
    }
    __builtin_amdgcn_sched_barrier(0);
    {
      const int gc = lane >> 4;
      bf16x8 af[4];
#pragma unroll
      for (int mi = 0; mi < 4; ++mi)
        af[mi] = frg(cA, wr * 64 + mi * 16 + (lane & 15), gc);
      __builtin_amdgcn_s_setprio(1);
#pragma unroll
      for (int ni = 0; ni < 2; ++ni) {
        bf16x8 b = frg(cB, wc * 32 + ni * 16 + (lane & 15), gc);
#pragma unroll
        for (int mi = 0; mi < 4; ++mi)
          acc[mi][ni] = __builtin_amdgcn_mfma_f32_16x16x32_bf16(af[mi], b, acc[mi][ni], 0, 0, 0);
      }
      __builtin_amdgcn_s_setprio(0);
    }
    if (it < NT - 1) {
      if (it < NT - 2) asm volatile("s_waitcnt vmcnt(2) lgkmcnt(0)" ::: "memory");
      else             asm volatile("s_waitcnt vmcnt(0) lgkmcnt(0)" ::: "memory");
      __builtin_amdgcn_s_barrier();
      __builtin_amdgcn_sched_barrier(0);
    }
    { char* t_ = cA; cA = nA; nA = xA; xA = t_;
      t_ = cB; cB = nB; nB = xB; xB = t_; }
  }
  const int rb = wr * 64 + 4 * (lane >> 4), cb = wc * 32 + (lane & 15);
#pragma unroll
  for (int mi = 0; mi < 4; ++mi)
#pragma unroll
    for (int r = 0; r < 4; ++r) {
      int grow = row0 + rb + mi * 16 + r;
      int t = rowmap[grow];
      if (t < 0) continue;
      float wgt = roww[grow];
#pragma unroll
      for (int ni = 0; ni < 2; ++ni)
        atomicAdd(&out[(size_t)t * Hh + n0 + cb + ni * 16], wgt * acc[mi][ni][r]);
    }
}

extern "C" void kernel_launch(void* const* d_in, const int* in_sizes, int n_in,
                              void* d_out, int out_size, void* d_ws, size_t ws_size,
                              hipStream_t stream) {
  const float* x  = (const float*)d_in[0];
  const float* gw = (const float*)d_in[1];
  const float* w1 = (const float*)d_in[2];
  const float* w3 = (const float*)d_in[3];
  const float* w2 = (const float*)d_in[4];
  float* out = (float*)d_out;
  float* logits = out + (size_t)Tt * Hh;
  char* ws = (char*)d_ws;
  int* ctrl = (int*)(ws + OFF_CTRL);
  int* tok_e = (int*)(ws + OFF_TOKE);
  float* tok_w = (float*)(ws + OFF_TOKW);
  int* rowmap = (int*)(ws + OFF_ROWMAP);
  float* roww = (float*)(ws + OFF_ROWW);
  unsigned short* Xg   = (unsigned short*)(ws + OFF_XG);
  unsigned short* G    = (unsigned short*)(ws + OFF_G);
  unsigned short* w13T = (unsigned short*)(ws + OFF_W13T);
  unsigned short* w2T  = (unsigned short*)(ws + OFF_W2T);

  hipMemsetAsync(ctrl, 0, 1024, stream);
  hipMemsetAsync(out, 0, (size_t)Tt * Hh * sizeof(float), stream);
  router_tc1<<<512 + 3584, 256, 0, stream>>>(x, gw, logits, tok_e, tok_w, ctrl, w1, w13T);
  offsets_kernel<<<1, 64, 0, stream>>>(ctrl);
  assign_kernel<<<8, 512, 0, stream>>>(ctrl, tok_e, tok_w, rowmap, roww);
  gather_tc3<<<2560 + 3584, 256, 0, stream>>>(x, ctrl, rowmap, Xg, w3, w13T);
  h13_tc2<<<dim3(28, 56), 1024, 0, stream>>>(Xg, w13T, ctrl, G, w2, w2T);
  ffn2_gemm<<<dim3(8, MAXT, 4), 512, 0, stream>>>(G, w2T, ctrl, rowmap, roww, out);
}